// Round 10
// baseline (459.955 us; speedup 1.0000x reference)
//
#include <hip/hip_runtime.h>
#include <cstdint>
#include <cstddef>

// Problem constants (fixed by the reference: B=8192, F=1024, N=4096)
#define B_DIM 8192
#define F_DIM 1024
#define N_DIM 4096

// R10: block tile 128x128, BK=128 fp8, but EIGHT waves (512 thr) of 64x32
// wave-tile (2x4 wave grid). acc 32 + af 32 + bf 16 regs -> fits the 128-reg
// cap of __launch_bounds__(512,4) -> 2 blocks/CU = 16 waves/CU (was ~11.6).
// Trades LDS read volume (x1.5, pipe ~42->63% busy) for +38% latency-hiding
// TLP -- the remaining axis after R6 (spills) and R7 (dbuf) failed.
// Kernels renamed (k_cvt / k_g1 / k_g2) for per-dispatch attribution.
#define BM 128
#define BN 128
#define BK 128

typedef float floatx4 __attribute__((ext_vector_type(4)));
typedef int intx4 __attribute__((ext_vector_type(4)));
typedef int intx8 __attribute__((ext_vector_type(8)));

typedef const __attribute__((address_space(1))) unsigned int* as1_u32cp;
typedef __attribute__((address_space(3))) unsigned int* as3_u32p;

// Async global->LDS 16B copy. LDS dest is wave-uniform base + lane*16.
__device__ __forceinline__ void gload_lds16(const uint8_t* g, uint8_t* l) {
    __builtin_amdgcn_global_load_lds((as1_u32cp)(const unsigned int*)g,
                                     (as3_u32p)(unsigned int*)l, 16, 0, 0);
}

__device__ __forceinline__ float hardswish_f(float l) {
    float g = fminf(fmaxf(l + 3.0f, 0.0f), 6.0f);
    return l * g * (1.0f / 6.0f);
}

// fp32 -> fp8 e4m3 for x|y|w (dst contiguous in ws) + rowsum-zero tail.
// One float4/thread: 16B/lane coalesced reads, 4B/lane coalesced stores.
__global__ __launch_bounds__(256) void k_cvt(
    const float* __restrict__ x, const float* __restrict__ y,
    const float* __restrict__ wt, uint8_t* __restrict__ dst,
    float* __restrict__ rowsum, int n4x, int n4w) {
    int i = blockIdx.x * 256 + threadIdx.x;
    int total = 2 * n4x + n4w;
    if (i >= total) {
        int r = i - total;
        if (r < B_DIM / 4) ((float4*)rowsum)[r] = make_float4(0.f, 0.f, 0.f, 0.f);
        return;
    }
    const float* src;
    int j;
    if (i < n4x) { src = x; j = i; }
    else if (i < 2 * n4x) { src = y; j = i - n4x; }
    else { src = wt; j = i - 2 * n4x; }
    float4 v = ((const float4*)src)[j];
    int p = __builtin_amdgcn_cvt_pk_fp8_f32(v.x, v.y, 0, false);
    p = __builtin_amdgcn_cvt_pk_fp8_f32(v.z, v.w, p, true);
    ((int*)dst)[i] = p;
}

// Shared GEMM body: C = A * B^T, fp8 e4m3, mfma_scale_f32_16x16x128_f8f6f4,
// unit scales. LDS XOR-swizzle in 16B chunks: slot (row,c) holds global chunk
// c^(row&7). A-frag (16x16x128): row=lane&15, k=quad*32+reg*4+byte -> chunks
// {(2q)^e,(2q+1)^e}, e=row&7. C/D: col=lane&15, row=quad*4+reg.
// 8 waves: wave w -> wm=w>>2 (row, 64 each), wn=w&3 (col, 32 each).
// MODE 1: epilogue sums exp(C) into rowsum (scores never hit HBM).
// MODE 2: prologue addv[128]=hardswish(log(rowsum)); epilogue direct stores
//         out = clamp(C + bias + addv, -1, 1)  (R8 transpose was neutral).
template <int MODE>
__device__ __forceinline__ void gemm_body(
    const uint8_t* __restrict__ A,
    const uint8_t* __restrict__ Bm,
    int K, int N,
    float* __restrict__ rowsum,
    const float* __restrict__ bias,
    float* __restrict__ out) {
    __shared__ __align__(16) uint8_t As[BM * BK];   // 16 KB
    __shared__ __align__(16) uint8_t Bs[BN * BK];   // 16 KB
    __shared__ float addv[BM];

    const int t = threadIdx.x;
    const int w = t >> 6;
    const int lane = t & 63;
    const int quad = lane >> 4;
    const int lc = lane & 15;
    const int wm = w >> 2;   // wave row (0..1), 64 rows each
    const int wn = w & 3;    // wave col (0..3), 32 cols each
    const int rowBase = blockIdx.y * BM;
    const int colBase = blockIdx.x * BN;

    if constexpr (MODE == 2) {
        // published by the K-loop's first __syncthreads()
        if (t < BM) addv[t] = hardswish_f(logf(rowsum[rowBase + t]));
    }

    floatx4 acc[4][2];
#pragma unroll
    for (int mi = 0; mi < 4; ++mi)
#pragma unroll
        for (int ni = 0; ni < 2; ++ni)
            acc[mi][ni] = (floatx4){0.f, 0.f, 0.f, 0.f};

    const int nIter = K / BK;
    for (int kt = 0; kt < nIter; ++kt) {
        __syncthreads();  // prior iteration's LDS reads complete (+ addv publish)
#pragma unroll
        for (int c = 0; c < 2; ++c) {
            const int idx = c * 512 + t;       // 0..1023 -> 1024 16B chunks each
            const int row = idx >> 3;          // 0..127
            const int cg = (idx & 7) ^ (row & 7);
            gload_lds16(A + (size_t)(rowBase + row) * K + kt * BK + cg * 16, As + idx * 16);
            gload_lds16(Bm + (size_t)(colBase + row) * K + kt * BK + cg * 16, Bs + idx * 16);
        }
        __syncthreads();  // drains vmcnt: staged data visible

        intx8 af[4], bf[2];
#pragma unroll
        for (int mi = 0; mi < 4; ++mi) {
            const int row = wm * 64 + mi * 16 + lc;
            const int e = row & 7;
            ((intx4*)&af[mi])[0] = *(const intx4*)(As + row * BK + ((2 * quad) ^ e) * 16);
            ((intx4*)&af[mi])[1] = *(const intx4*)(As + row * BK + ((2 * quad + 1) ^ e) * 16);
        }
#pragma unroll
        for (int ni = 0; ni < 2; ++ni) {
            const int row = wn * 32 + ni * 16 + lc;
            const int e = row & 7;
            ((intx4*)&bf[ni])[0] = *(const intx4*)(Bs + row * BK + ((2 * quad) ^ e) * 16);
            ((intx4*)&bf[ni])[1] = *(const intx4*)(Bs + row * BK + ((2 * quad + 1) ^ e) * 16);
        }
#pragma unroll
        for (int mi = 0; mi < 4; ++mi)
#pragma unroll
            for (int ni = 0; ni < 2; ++ni)
                acc[mi][ni] = __builtin_amdgcn_mfma_scale_f32_16x16x128_f8f6f4(
                    af[mi], bf[ni], acc[mi][ni],
                    0, 0,                      // cbsz=fp8(e4m3), blgp=fp8(e4m3)
                    0, 0x7F7F7F7F,             // A scale: 1.0
                    0, 0x7F7F7F7F);            // B scale: 1.0
    }

    if constexpr (MODE == 1) {
        // sum exp over this wave's 32 columns for each of its 64 rows
#pragma unroll
        for (int mi = 0; mi < 4; ++mi) {
#pragma unroll
            for (int r = 0; r < 4; ++r) {
                float p = __expf(acc[mi][0][r]) + __expf(acc[mi][1][r]);
                // butterfly over the 16 columns held by this quad's 16 lanes
                p += __shfl_xor(p, 1, 16);
                p += __shfl_xor(p, 2, 16);
                p += __shfl_xor(p, 4, 16);
                p += __shfl_xor(p, 8, 16);
                if (lc == 0) {
                    int row = rowBase + wm * 64 + mi * 16 + quad * 4 + r;
                    atomicAdd(&rowsum[row], p);
                }
            }
        }
    } else {
#pragma unroll
        for (int mi = 0; mi < 4; ++mi) {
            const int lrow = wm * 64 + mi * 16 + quad * 4;
            float av[4];
#pragma unroll
            for (int r = 0; r < 4; ++r) av[r] = addv[lrow + r];
#pragma unroll
            for (int ni = 0; ni < 2; ++ni) {
                const int col = colBase + wn * 32 + ni * 16 + lc;
                const float bv = bias[col];
#pragma unroll
                for (int r = 0; r < 4; ++r) {
                    float v = acc[mi][ni][r] + bv + av[r];
                    v = fminf(fmaxf(v, -1.0f), 1.0f);
                    out[(size_t)(rowBase + lrow + r) * N + col] = v;
                }
            }
        }
    }
}

__global__ __launch_bounds__(512, 4) void k_g1(
    const uint8_t* __restrict__ A, const uint8_t* __restrict__ Bm,
    int K, int N, float* __restrict__ rowsum) {
    gemm_body<1>(A, Bm, K, N, rowsum, nullptr, nullptr);
}

__global__ __launch_bounds__(512, 4) void k_g2(
    const uint8_t* __restrict__ A, const uint8_t* __restrict__ Bm,
    int K, int N, float* __restrict__ rowsum,
    const float* __restrict__ bias, float* __restrict__ out) {
    gemm_body<2>(A, Bm, K, N, rowsum, bias, out);
}

extern "C" void kernel_launch(void* const* d_in, const int* in_sizes, int n_in,
                              void* d_out, int out_size, void* d_ws, size_t ws_size,
                              hipStream_t stream) {
    const float* x = (const float*)d_in[0];     // [B, F]
    const float* y = (const float*)d_in[1];     // [B, F]
    const float* wt = (const float*)d_in[2];    // [N, F]
    const float* bias = (const float*)d_in[3];  // [N]
    float* out = (float*)d_out;                 // [B, N]

    // Workspace: xq 8MB | yq 8MB | wq 4MB | rowsum 32KB (contiguous fp8 dst)
    uint8_t* xq = (uint8_t*)d_ws;
    uint8_t* yq = xq + (size_t)B_DIM * F_DIM;
    uint8_t* wq = yq + (size_t)B_DIM * F_DIM;
    float* rowsum = (float*)(wq + (size_t)N_DIM * F_DIM);

    const int n4_x = B_DIM * F_DIM / 4;
    const int n4_w = N_DIM * F_DIM / 4;
    const int total_thr = 2 * n4_x + n4_w + B_DIM / 4;  // cvt + rowsum-zero tail
    k_cvt<<<(total_thr + 255) / 256, 256, 0, stream>>>(
        x, y, wt, xq, rowsum, n4_x, n4_w);

    // Stage 1: scores = x . y^T, fused exp-rowsum
    k_g1<<<dim3(B_DIM / BN, B_DIM / BM), 512, 0, stream>>>(
        xq, yq, F_DIM, B_DIM, rowsum);

    // Stage 2: out = y . w^T + bias + hardswish(log(rowsum)), clamped
    k_g2<<<dim3(N_DIM / BN, B_DIM / BM), 512, 0, stream>>>(
        yq, wq, F_DIM, N_DIM, rowsum, bias, out);
}

// Round 11
// 342.812 us; speedup vs baseline: 1.3417x; 1.3417x over previous
//
#include <hip/hip_runtime.h>
#include <cstdint>
#include <cstddef>

// Problem constants (fixed by the reference: B=8192, F=1024, N=4096)
#define B_DIM 8192
#define F_DIM 1024
#define N_DIM 4096

// GEMM tiling: 128x128 block tile, 4 waves (2x2), 64x64 per wave, BK=128 fp8.
// Structural experiments all regressed vs this shape:
//   R4 256x128 tile -> reg cliff. R6 forced 128 regs -> scratch spills.
//   R7 LDS double-buffer -> occupancy loss + vmcnt(0) drain anyway.
//   R10 8-wave 64x32 tiles -> half the MFMA per wave per barrier, 1.5x LDS.
// Ceiling model: wave 64x64 @ BK=128 demands ~175 B/cy LDS vs 128 peak ->
// MfmaUtil caps ~25-35% (matches m148's 1628 TF on the same structure).
// R11: exact revert to R8 bodies (best: 336.9 us) + distinct kernel names
// for per-dispatch attribution (k_cvt / k_g1 / k_g2).
#define BM 128
#define BN 128
#define BK 128

typedef float floatx4 __attribute__((ext_vector_type(4)));
typedef int intx4 __attribute__((ext_vector_type(4)));
typedef int intx8 __attribute__((ext_vector_type(8)));

typedef const __attribute__((address_space(1))) unsigned int* as1_u32cp;
typedef __attribute__((address_space(3))) unsigned int* as3_u32p;

// Async global->LDS 16B copy. LDS dest is wave-uniform base + lane*16.
__device__ __forceinline__ void gload_lds16(const uint8_t* g, uint8_t* l) {
    __builtin_amdgcn_global_load_lds((as1_u32cp)(const unsigned int*)g,
                                     (as3_u32p)(unsigned int*)l, 16, 0, 0);
}

__device__ __forceinline__ float hardswish_f(float l) {
    float g = fminf(fmaxf(l + 3.0f, 0.0f), 6.0f);
    return l * g * (1.0f / 6.0f);
}

// fp32 -> fp8 e4m3 for x|y|w (dst contiguous in ws) + rowsum-zero tail.
// One float4/thread: 16B/lane coalesced reads, 4B/lane coalesced stores.
__global__ __launch_bounds__(256) void k_cvt(
    const float* __restrict__ x, const float* __restrict__ y,
    const float* __restrict__ wt, uint8_t* __restrict__ dst,
    float* __restrict__ rowsum, int n4x, int n4w) {
    int i = blockIdx.x * 256 + threadIdx.x;
    int total = 2 * n4x + n4w;
    if (i >= total) {
        int r = i - total;
        if (r < B_DIM / 4) ((float4*)rowsum)[r] = make_float4(0.f, 0.f, 0.f, 0.f);
        return;
    }
    const float* src;
    int j;
    if (i < n4x) { src = x; j = i; }
    else if (i < 2 * n4x) { src = y; j = i - n4x; }
    else { src = wt; j = i - 2 * n4x; }
    float4 v = ((const float4*)src)[j];
    int p = __builtin_amdgcn_cvt_pk_fp8_f32(v.x, v.y, 0, false);
    p = __builtin_amdgcn_cvt_pk_fp8_f32(v.z, v.w, p, true);
    ((int*)dst)[i] = p;
}

// C = A * B^T, A[M][K], Bm[N][K] row-major fp8 e4m3, fp32 accumulate via
// mfma_scale_f32_16x16x128_f8f6f4 with unit scales (E8M0 0x7F = 2^0).
// LDS XOR-swizzled in 16B chunks: slot (row,c) holds global chunk c^(row&7).
// A-fragment (16x16x128): row=lane&15, k = quad*32 + reg*4 + byte
// -> 32 contiguous bytes = swizzled chunks {(2q)^e, (2q+1)^e}, e=row&7.
// C/D layout: col=lane&15, row=quad*4+reg.
// MODE 1: epilogue sums exp(C[i][j]) into rowsum[i] (scores never hit HBM).
// MODE 2: prologue addv[128]=hardswish(log(rowsum)); epilogue transposed
//         through LDS (stride 132 floats) for coalesced float4 stores of
//         out = clamp(C + bias + addv, -1, 1).
template <int MODE>
__device__ __forceinline__ void gemm_body(
    const uint8_t* __restrict__ A,
    const uint8_t* __restrict__ Bm,
    int K, int N,
    float* __restrict__ rowsum,
    const float* __restrict__ bias,
    float* __restrict__ out) {
    // 33.8 KB: staging (32 KB) during K-loop; 64x132 float pad-buffer after.
    __shared__ __align__(16) uint8_t smem[64 * 132 * 4];
    __shared__ float addv[BM];     // separate: must not alias epi
    uint8_t* As = smem;            // 16 KB
    uint8_t* Bs = smem + 16384;    // 16 KB
    float* epi = (float*)smem;     // MODE 2 epilogue reuse

    const int t = threadIdx.x;
    const int w = t >> 6;
    const int lane = t & 63;
    const int quad = lane >> 4;
    const int lc = lane & 15;
    const int wm = w >> 1;   // wave row (0..1), 64 rows each
    const int wn = w & 1;    // wave col (0..1), 64 cols each
    const int rowBase = blockIdx.y * BM;
    const int colBase = blockIdx.x * BN;

    if constexpr (MODE == 2) {
        // one log per thread; published by the K-loop's first __syncthreads()
        if (t < BM) addv[t] = hardswish_f(logf(rowsum[rowBase + t]));
    }

    floatx4 acc[4][4];
#pragma unroll
    for (int mi = 0; mi < 4; ++mi)
#pragma unroll
        for (int ni = 0; ni < 4; ++ni)
            acc[mi][ni] = (floatx4){0.f, 0.f, 0.f, 0.f};

    const int nIter = K / BK;
    for (int kt = 0; kt < nIter; ++kt) {
        __syncthreads();  // prior iteration's LDS reads complete (+ addv publish)
#pragma unroll
        for (int c = 0; c < 4; ++c) {
            const int idx = c * 256 + t;       // 0..1023 -> 1024 16B chunks each
            const int row = idx >> 3;          // 0..127
            const int cg = (idx & 7) ^ (row & 7);
            gload_lds16(A + (size_t)(rowBase + row) * K + kt * BK + cg * 16, As + idx * 16);
            gload_lds16(Bm + (size_t)(colBase + row) * K + kt * BK + cg * 16, Bs + idx * 16);
        }
        __syncthreads();  // drains vmcnt: staged data visible

        intx8 af[4], bf[4];
#pragma unroll
        for (int mi = 0; mi < 4; ++mi) {
            const int row = wm * 64 + mi * 16 + lc;
            const int e = row & 7;
            ((intx4*)&af[mi])[0] = *(const intx4*)(As + row * BK + ((2 * quad) ^ e) * 16);
            ((intx4*)&af[mi])[1] = *(const intx4*)(As + row * BK + ((2 * quad + 1) ^ e) * 16);
        }
#pragma unroll
        for (int ni = 0; ni < 4; ++ni) {
            const int row = wn * 64 + ni * 16 + lc;
            const int e = row & 7;
            ((intx4*)&bf[ni])[0] = *(const intx4*)(Bs + row * BK + ((2 * quad) ^ e) * 16);
            ((intx4*)&bf[ni])[1] = *(const intx4*)(Bs + row * BK + ((2 * quad + 1) ^ e) * 16);
        }
#pragma unroll
        for (int mi = 0; mi < 4; ++mi)
#pragma unroll
            for (int ni = 0; ni < 4; ++ni)
                acc[mi][ni] = __builtin_amdgcn_mfma_scale_f32_16x16x128_f8f6f4(
                    af[mi], bf[ni], acc[mi][ni],
                    0, 0,                      // cbsz=fp8(e4m3), blgp=fp8(e4m3)
                    0, 0x7F7F7F7F,             // A scale: 1.0
                    0, 0x7F7F7F7F);            // B scale: 1.0
    }

    if constexpr (MODE == 1) {
        // sum exp over this wave's 64 columns for each of its 64 rows
#pragma unroll
        for (int mi = 0; mi < 4; ++mi) {
#pragma unroll
            for (int r = 0; r < 4; ++r) {
                float p = 0.f;
#pragma unroll
                for (int ni = 0; ni < 4; ++ni) p += __expf(acc[mi][ni][r]);
                // butterfly over the 16 columns held by this quad's 16 lanes
                p += __shfl_xor(p, 1, 16);
                p += __shfl_xor(p, 2, 16);
                p += __shfl_xor(p, 4, 16);
                p += __shfl_xor(p, 8, 16);
                if (lc == 0) {
                    int row = rowBase + wm * 64 + mi * 16 + quad * 4 + r;
                    atomicAdd(&rowsum[row], p);
                }
            }
        }
    } else {
        // Two halves (64 rows each): wave-row h dumps its (bias+addv+clamp)ed
        // tile into epi[64][132], then all 256 threads store coalesced float4.
#pragma unroll
        for (int h = 0; h < 2; ++h) {
            __syncthreads();  // epi free (staging reads / prior half done)
            if (wm == h) {
#pragma unroll
                for (int mi = 0; mi < 4; ++mi) {
                    const int lr0 = mi * 16 + quad * 4;    // local row 0..60
#pragma unroll
                    for (int ni = 0; ni < 4; ++ni) {
                        const int c = wn * 64 + ni * 16 + lc;
                        const float bv = bias[colBase + c];
#pragma unroll
                        for (int r = 0; r < 4; ++r) {
                            float v = acc[mi][ni][r] + bv + addv[h * 64 + lr0 + r];
                            v = fminf(fmaxf(v, -1.0f), 1.0f);
                            epi[(lr0 + r) * 132 + c] = v;
                        }
                    }
                }
            }
            __syncthreads();  // epi visible to all
#pragma unroll
            for (int k = 0; k < 8; ++k) {
                const int idx = k * 256 + t;     // 0..2047
                const int row = idx >> 5;        // 0..63
                const int c4 = (idx & 31) * 4;   // 0..124
                float4 v = *(const float4*)&epi[row * 132 + c4];
                *(float4*)&out[(size_t)(rowBase + h * 64 + row) * N + colBase + c4] = v;
            }
        }
    }
}

__global__ __launch_bounds__(256, 3) void k_g1(
    const uint8_t* __restrict__ A, const uint8_t* __restrict__ Bm,
    int K, int N, float* __restrict__ rowsum) {
    gemm_body<1>(A, Bm, K, N, rowsum, nullptr, nullptr);
}

__global__ __launch_bounds__(256, 3) void k_g2(
    const uint8_t* __restrict__ A, const uint8_t* __restrict__ Bm,
    int K, int N, float* __restrict__ rowsum,
    const float* __restrict__ bias, float* __restrict__ out) {
    gemm_body<2>(A, Bm, K, N, rowsum, bias, out);
}

extern "C" void kernel_launch(void* const* d_in, const int* in_sizes, int n_in,
                              void* d_out, int out_size, void* d_ws, size_t ws_size,
                              hipStream_t stream) {
    const float* x = (const float*)d_in[0];     // [B, F]
    const float* y = (const float*)d_in[1];     // [B, F]
    const float* wt = (const float*)d_in[2];    // [N, F]
    const float* bias = (const float*)d_in[3];  // [N]
    float* out = (float*)d_out;                 // [B, N]

    // Workspace: xq 8MB | yq 8MB | wq 4MB | rowsum 32KB (contiguous fp8 dst)
    uint8_t* xq = (uint8_t*)d_ws;
    uint8_t* yq = xq + (size_t)B_DIM * F_DIM;
    uint8_t* wq = yq + (size_t)B_DIM * F_DIM;
    float* rowsum = (float*)(wq + (size_t)N_DIM * F_DIM);

    const int n4_x = B_DIM * F_DIM / 4;
    const int n4_w = N_DIM * F_DIM / 4;
    const int total_thr = 2 * n4_x + n4_w + B_DIM / 4;  // cvt + rowsum-zero tail
    k_cvt<<<(total_thr + 255) / 256, 256, 0, stream>>>(
        x, y, wt, xq, rowsum, n4_x, n4_w);

    // Stage 1: scores = x . y^T, fused exp-rowsum
    k_g1<<<dim3(B_DIM / BN, B_DIM / BM), 256, 0, stream>>>(
        xq, yq, F_DIM, B_DIM, rowsum);

    // Stage 2: out = y . w^T + bias + hardswish(log(rowsum)), clamped
    k_g2<<<dim3(N_DIM / BN, B_DIM / BM), 256, 0, stream>>>(
        yq, wq, F_DIM, N_DIM, rowsum, bias, out);
}

// Round 12
// 334.255 us; speedup vs baseline: 1.3761x; 1.0256x over previous
//
#include <hip/hip_runtime.h>
#include <cstdint>
#include <cstddef>

// Problem constants (fixed by the reference: B=8192, F=1024, N=4096)
#define B_DIM 8192
#define F_DIM 1024
#define N_DIM 4096

// GEMM tiling: 128x128 block tile, 4 waves (2x2), 64x64 per wave, BK=128 fp8.
// Structural experiments all regressed vs this shape (R4 bigger tile: reg
// cliff; R6 reg squeeze: spills; R7 dbuf: occupancy loss; R10 8-wave: less
// MFMA/wave/barrier). This is the verified local optimum (~122 us for G1).
// R12: split k_g1 into TWO half-grid dispatches (column halves; rowsum
// atomics compose) so each is ~62 us -> anything slower (k_g2? k_cvt?)
// surfaces in the profiler's top-5 window. Expected perf-neutral.
#define BM 128
#define BN 128
#define BK 128

typedef float floatx4 __attribute__((ext_vector_type(4)));
typedef int intx4 __attribute__((ext_vector_type(4)));
typedef int intx8 __attribute__((ext_vector_type(8)));

typedef const __attribute__((address_space(1))) unsigned int* as1_u32cp;
typedef __attribute__((address_space(3))) unsigned int* as3_u32p;

// Async global->LDS 16B copy. LDS dest is wave-uniform base + lane*16.
__device__ __forceinline__ void gload_lds16(const uint8_t* g, uint8_t* l) {
    __builtin_amdgcn_global_load_lds((as1_u32cp)(const unsigned int*)g,
                                     (as3_u32p)(unsigned int*)l, 16, 0, 0);
}

__device__ __forceinline__ float hardswish_f(float l) {
    float g = fminf(fmaxf(l + 3.0f, 0.0f), 6.0f);
    return l * g * (1.0f / 6.0f);
}

// fp32 -> fp8 e4m3 for x|y|w (dst contiguous in ws) + rowsum-zero tail.
// One float4/thread: 16B/lane coalesced reads, 4B/lane coalesced stores.
__global__ __launch_bounds__(256) void k_cvt(
    const float* __restrict__ x, const float* __restrict__ y,
    const float* __restrict__ wt, uint8_t* __restrict__ dst,
    float* __restrict__ rowsum, int n4x, int n4w) {
    int i = blockIdx.x * 256 + threadIdx.x;
    int total = 2 * n4x + n4w;
    if (i >= total) {
        int r = i - total;
        if (r < B_DIM / 4) ((float4*)rowsum)[r] = make_float4(0.f, 0.f, 0.f, 0.f);
        return;
    }
    const float* src;
    int j;
    if (i < n4x) { src = x; j = i; }
    else if (i < 2 * n4x) { src = y; j = i - n4x; }
    else { src = wt; j = i - 2 * n4x; }
    float4 v = ((const float4*)src)[j];
    int p = __builtin_amdgcn_cvt_pk_fp8_f32(v.x, v.y, 0, false);
    p = __builtin_amdgcn_cvt_pk_fp8_f32(v.z, v.w, p, true);
    ((int*)dst)[i] = p;
}

// C = A * B^T, A[M][K], Bm[N][K] row-major fp8 e4m3, fp32 accumulate via
// mfma_scale_f32_16x16x128_f8f6f4 with unit scales (E8M0 0x7F = 2^0).
// LDS XOR-swizzled in 16B chunks: slot (row,c) holds global chunk c^(row&7).
// A-fragment (16x16x128): row=lane&15, k = quad*32 + reg*4 + byte
// -> 32 contiguous bytes = swizzled chunks {(2q)^e, (2q+1)^e}, e=row&7.
// C/D layout: col=lane&15, row=quad*4+reg.
// MODE 1: epilogue sums exp(C[i][j]) into rowsum[i] (scores never hit HBM).
// MODE 2: prologue addv[128]=hardswish(log(rowsum)); epilogue transposed
//         through LDS (stride 132 floats) for coalesced float4 stores of
//         out = clamp(C + bias + addv, -1, 1).
template <int MODE>
__device__ __forceinline__ void gemm_body(
    const uint8_t* __restrict__ A,
    const uint8_t* __restrict__ Bm,
    int K, int N, int colOff,
    float* __restrict__ rowsum,
    const float* __restrict__ bias,
    float* __restrict__ out) {
    // 33.8 KB: staging (32 KB) during K-loop; 64x132 float pad-buffer after.
    __shared__ __align__(16) uint8_t smem[64 * 132 * 4];
    __shared__ float addv[BM];     // separate: must not alias epi
    uint8_t* As = smem;            // 16 KB
    uint8_t* Bs = smem + 16384;    // 16 KB
    float* epi = (float*)smem;     // MODE 2 epilogue reuse

    const int t = threadIdx.x;
    const int w = t >> 6;
    const int lane = t & 63;
    const int quad = lane >> 4;
    const int lc = lane & 15;
    const int wm = w >> 1;   // wave row (0..1), 64 rows each
    const int wn = w & 1;    // wave col (0..1), 64 cols each
    const int rowBase = blockIdx.y * BM;
    const int colBase = blockIdx.x * BN + colOff;

    if constexpr (MODE == 2) {
        // one log per thread; published by the K-loop's first __syncthreads()
        if (t < BM) addv[t] = hardswish_f(logf(rowsum[rowBase + t]));
    }

    floatx4 acc[4][4];
#pragma unroll
    for (int mi = 0; mi < 4; ++mi)
#pragma unroll
        for (int ni = 0; ni < 4; ++ni)
            acc[mi][ni] = (floatx4){0.f, 0.f, 0.f, 0.f};

    const int nIter = K / BK;
    for (int kt = 0; kt < nIter; ++kt) {
        __syncthreads();  // prior iteration's LDS reads complete (+ addv publish)
#pragma unroll
        for (int c = 0; c < 4; ++c) {
            const int idx = c * 256 + t;       // 0..1023 -> 1024 16B chunks each
            const int row = idx >> 3;          // 0..127
            const int cg = (idx & 7) ^ (row & 7);
            gload_lds16(A + (size_t)(rowBase + row) * K + kt * BK + cg * 16, As + idx * 16);
            gload_lds16(Bm + (size_t)(colBase + row) * K + kt * BK + cg * 16, Bs + idx * 16);
        }
        __syncthreads();  // drains vmcnt: staged data visible

        intx8 af[4], bf[4];
#pragma unroll
        for (int mi = 0; mi < 4; ++mi) {
            const int row = wm * 64 + mi * 16 + lc;
            const int e = row & 7;
            ((intx4*)&af[mi])[0] = *(const intx4*)(As + row * BK + ((2 * quad) ^ e) * 16);
            ((intx4*)&af[mi])[1] = *(const intx4*)(As + row * BK + ((2 * quad + 1) ^ e) * 16);
        }
#pragma unroll
        for (int ni = 0; ni < 4; ++ni) {
            const int row = wn * 64 + ni * 16 + lc;
            const int e = row & 7;
            ((intx4*)&bf[ni])[0] = *(const intx4*)(Bs + row * BK + ((2 * quad) ^ e) * 16);
            ((intx4*)&bf[ni])[1] = *(const intx4*)(Bs + row * BK + ((2 * quad + 1) ^ e) * 16);
        }
#pragma unroll
        for (int mi = 0; mi < 4; ++mi)
#pragma unroll
            for (int ni = 0; ni < 4; ++ni)
                acc[mi][ni] = __builtin_amdgcn_mfma_scale_f32_16x16x128_f8f6f4(
                    af[mi], bf[ni], acc[mi][ni],
                    0, 0,                      // cbsz=fp8(e4m3), blgp=fp8(e4m3)
                    0, 0x7F7F7F7F,             // A scale: 1.0
                    0, 0x7F7F7F7F);            // B scale: 1.0
    }

    if constexpr (MODE == 1) {
        // sum exp over this wave's 64 columns for each of its 64 rows
#pragma unroll
        for (int mi = 0; mi < 4; ++mi) {
#pragma unroll
            for (int r = 0; r < 4; ++r) {
                float p = 0.f;
#pragma unroll
                for (int ni = 0; ni < 4; ++ni) p += __expf(acc[mi][ni][r]);
                // butterfly over the 16 columns held by this quad's 16 lanes
                p += __shfl_xor(p, 1, 16);
                p += __shfl_xor(p, 2, 16);
                p += __shfl_xor(p, 4, 16);
                p += __shfl_xor(p, 8, 16);
                if (lc == 0) {
                    int row = rowBase + wm * 64 + mi * 16 + quad * 4 + r;
                    atomicAdd(&rowsum[row], p);
                }
            }
        }
    } else {
        // Two halves (64 rows each): wave-row h dumps its (bias+addv+clamp)ed
        // tile into epi[64][132], then all 256 threads store coalesced float4.
#pragma unroll
        for (int h = 0; h < 2; ++h) {
            __syncthreads();  // epi free (staging reads / prior half done)
            if (wm == h) {
#pragma unroll
                for (int mi = 0; mi < 4; ++mi) {
                    const int lr0 = mi * 16 + quad * 4;    // local row 0..60
#pragma unroll
                    for (int ni = 0; ni < 4; ++ni) {
                        const int c = wn * 64 + ni * 16 + lc;
                        const float bv = bias[colBase + c];
#pragma unroll
                        for (int r = 0; r < 4; ++r) {
                            float v = acc[mi][ni][r] + bv + addv[h * 64 + lr0 + r];
                            v = fminf(fmaxf(v, -1.0f), 1.0f);
                            epi[(lr0 + r) * 132 + c] = v;
                        }
                    }
                }
            }
            __syncthreads();  // epi visible to all
#pragma unroll
            for (int k = 0; k < 8; ++k) {
                const int idx = k * 256 + t;     // 0..2047
                const int row = idx >> 5;        // 0..63
                const int c4 = (idx & 31) * 4;   // 0..124
                float4 v = *(const float4*)&epi[row * 132 + c4];
                *(float4*)&out[(size_t)(rowBase + h * 64 + row) * N + colBase + c4] = v;
            }
        }
    }
}

__global__ __launch_bounds__(256, 3) void k_g1(
    const uint8_t* __restrict__ A, const uint8_t* __restrict__ Bm,
    int K, int N, int colOff, float* __restrict__ rowsum) {
    gemm_body<1>(A, Bm, K, N, colOff, rowsum, nullptr, nullptr);
}

__global__ __launch_bounds__(256, 3) void k_g2(
    const uint8_t* __restrict__ A, const uint8_t* __restrict__ Bm,
    int K, int N, float* __restrict__ rowsum,
    const float* __restrict__ bias, float* __restrict__ out) {
    gemm_body<2>(A, Bm, K, N, 0, rowsum, bias, out);
}

extern "C" void kernel_launch(void* const* d_in, const int* in_sizes, int n_in,
                              void* d_out, int out_size, void* d_ws, size_t ws_size,
                              hipStream_t stream) {
    const float* x = (const float*)d_in[0];     // [B, F]
    const float* y = (const float*)d_in[1];     // [B, F]
    const float* wt = (const float*)d_in[2];    // [N, F]
    const float* bias = (const float*)d_in[3];  // [N]
    float* out = (float*)d_out;                 // [B, N]

    // Workspace: xq 8MB | yq 8MB | wq 4MB | rowsum 32KB (contiguous fp8 dst)
    uint8_t* xq = (uint8_t*)d_ws;
    uint8_t* yq = xq + (size_t)B_DIM * F_DIM;
    uint8_t* wq = yq + (size_t)B_DIM * F_DIM;
    float* rowsum = (float*)(wq + (size_t)N_DIM * F_DIM);

    const int n4_x = B_DIM * F_DIM / 4;
    const int n4_w = N_DIM * F_DIM / 4;
    const int total_thr = 2 * n4_x + n4_w + B_DIM / 4;  // cvt + rowsum-zero tail
    k_cvt<<<(total_thr + 255) / 256, 256, 0, stream>>>(
        x, y, wt, xq, rowsum, n4_x, n4_w);

    // Stage 1: scores = x . y^T, fused exp-rowsum -- split into column halves
    // so each dispatch is ~62 us and slower kernels surface in the profile.
    k_g1<<<dim3(B_DIM / BN / 2, B_DIM / BM), 256, 0, stream>>>(
        xq, yq, F_DIM, B_DIM, 0, rowsum);
    k_g1<<<dim3(B_DIM / BN / 2, B_DIM / BM), 256, 0, stream>>>(
        xq, yq, F_DIM, B_DIM, B_DIM / 2, rowsum);

    // Stage 2: out = y . w^T + bias + hardswish(log(rowsum)), clamped
    k_g2<<<dim3(N_DIM / BN, B_DIM / BM), 256, 0, stream>>>(
        yq, wq, F_DIM, N_DIM, rowsum, bias, out);
}